// Round 1
// 665.796 us; speedup vs baseline: 1.3992x; 1.3992x over previous
//
#include <hip/hip_runtime.h>

typedef __attribute__((ext_vector_type(4))) float floatx4;
typedef __attribute__((ext_vector_type(8))) short bf16x8;
typedef __attribute__((ext_vector_type(2))) unsigned int uintx2;
typedef __attribute__((ext_vector_type(4))) unsigned int uintx4;

#define HW   4096
#define CIN  512
#define CODE 256
#define MEM  20
#define NCLS 4
#define NB   32

// ---------------------------------------------------------------------------
// fp32 -> bf16 round-to-nearest-even; returns rounded bits in HIGH 16 bits.
// ---------------------------------------------------------------------------
__device__ __forceinline__ unsigned bf16rn(float f) {
    unsigned u = __float_as_uint(f);
    return u + 0x7fffu + ((u >> 16) & 1u);
}

// LDS slot swizzle: 4 x 16B slots per 64B row, XOR by row bits 2..3
__device__ __forceinline__ int swz(int row, int slot) {
    return slot ^ ((row >> 2) & 3);
}

// ---------------------------------------------------------------------------
// Kernel 1: x = Wp @ feats + bp via bf16x3 split-precision MFMA.
//   x = Ah@Bh + Ah@Bl + Al@Bh  (error ~2^-18 rel, accumulate fp32)
// Tile 128(o) x 128(n), BK=32, 4 waves (each 64x64, 4x4 frags of 16x16x32).
// Double-buffered LDS (64 KiB exactly -> 2 blocks/CU), 1 barrier per K-step.
// Writes x into out[b][256+o][n] (concat second half).
// ---------------------------------------------------------------------------
__global__ __launch_bounds__(256, 2) void gemm_proj_bf16x3(
    const float* __restrict__ feats,
    const float* __restrict__ Wp,
    const float* __restrict__ bp,
    float* __restrict__ out)
{
    // [buf][0=Ah,1=Al,2=Bh,3=Bl][row][32 bf16]  = 65536 B
    __shared__ unsigned short lds[2][4][128][32];

    const int b   = blockIdx.z;
    const int n0  = blockIdx.x * 128;
    const int o0  = blockIdx.y * 128;
    const int tid = threadIdx.x;
    const int lane = tid & 63;
    const int wid  = tid >> 6;
    const int wm = (wid >> 1) * 64;   // wave m-offset in tile
    const int wn = (wid & 1) * 64;    // wave n-offset in tile
    const int lr = lane & 15;         // frag row/col lane index
    const int lg = lane >> 4;         // frag k-group (slot)

    // staging maps
    const int ar = tid >> 3;          // 0..31  A row base
    const int ac = tid & 7;           // 0..7   A k-quad
    const int bn = tid & 127;         // B column within tile
    const int bk = (tid >> 7) * 16;   // 0/16   B k base

    const float* fb = feats + (size_t)b * CIN * HW + n0 + bn;
    const float* wa = Wp + (size_t)(o0 + ar) * CIN + ac * 4;

    floatx4 acc[4][4];
#pragma unroll
    for (int i = 0; i < 4; ++i)
#pragma unroll
        for (int j = 0; j < 4; ++j)
#pragma unroll
            for (int r = 0; r < 4; ++r) acc[i][j][r] = 0.f;

    floatx4 av[4];
    float   bv[16];

#define G_LOAD(K0)                                                            \
    {                                                                         \
        _Pragma("unroll")                                                     \
        for (int i = 0; i < 4; ++i)                                           \
            av[i] = *(const floatx4*)(wa + (size_t)(32 * i) * CIN + (K0));    \
        _Pragma("unroll")                                                     \
        for (int j = 0; j < 16; ++j)                                          \
            bv[j] = fb[(size_t)((K0) + bk + j) * HW];                         \
    }

#define STAGE(BUF)                                                            \
    {                                                                         \
        _Pragma("unroll")                                                     \
        for (int i = 0; i < 4; ++i) {                                         \
            const int m = ar + 32 * i;                                        \
            unsigned h[4], l[4];                                              \
            _Pragma("unroll")                                                 \
            for (int e = 0; e < 4; ++e) {                                     \
                unsigned r = bf16rn(av[i][e]);                                \
                float hf = __uint_as_float(r & 0xffff0000u);                  \
                h[e] = r;                                                     \
                l[e] = bf16rn(av[i][e] - hf);                                 \
            }                                                                 \
            uintx2 tH, tL;                                                    \
            tH[0] = (h[0] >> 16) | (h[1] & 0xffff0000u);                      \
            tH[1] = (h[2] >> 16) | (h[3] & 0xffff0000u);                      \
            tL[0] = (l[0] >> 16) | (l[1] & 0xffff0000u);                      \
            tL[1] = (l[2] >> 16) | (l[3] & 0xffff0000u);                      \
            const int sA = swz(m, ac >> 1) * 8 + (ac & 1) * 4;                \
            *(uintx2*)&lds[BUF][0][m][sA] = tH;                               \
            *(uintx2*)&lds[BUF][1][m][sA] = tL;                               \
        }                                                                     \
        unsigned ph[8], pl[8];                                                \
        _Pragma("unroll")                                                     \
        for (int p = 0; p < 8; ++p) {                                         \
            unsigned r0 = bf16rn(bv[2 * p]), r1 = bf16rn(bv[2 * p + 1]);      \
            float h0 = __uint_as_float(r0 & 0xffff0000u);                     \
            float h1 = __uint_as_float(r1 & 0xffff0000u);                     \
            unsigned q0 = bf16rn(bv[2 * p] - h0);                             \
            unsigned q1 = bf16rn(bv[2 * p + 1] - h1);                         \
            ph[p] = (r0 >> 16) | (r1 & 0xffff0000u);                          \
            pl[p] = (q0 >> 16) | (q1 & 0xffff0000u);                          \
        }                                                                     \
        const int sb2 = (tid >> 7) * 2;                                       \
        _Pragma("unroll")                                                     \
        for (int u = 0; u < 2; ++u) {                                         \
            const int s = swz(bn, sb2 + u) * 8;                               \
            uintx4 tB, tC;                                                    \
            tB[0] = ph[4 * u];     tB[1] = ph[4 * u + 1];                     \
            tB[2] = ph[4 * u + 2]; tB[3] = ph[4 * u + 3];                     \
            tC[0] = pl[4 * u];     tC[1] = pl[4 * u + 1];                     \
            tC[2] = pl[4 * u + 2]; tC[3] = pl[4 * u + 3];                     \
            *(uintx4*)&lds[BUF][2][bn][s] = tB;                               \
            *(uintx4*)&lds[BUF][3][bn][s] = tC;                               \
        }                                                                     \
    }

#define COMPUTE(BUF)                                                          \
    {                                                                         \
        bf16x8 fah[4], fal[4], fbh[4], fbl[4];                                \
        _Pragma("unroll")                                                     \
        for (int i = 0; i < 4; ++i) {                                         \
            const int rm = wm + i * 16 + lr;                                  \
            const int rn = wn + i * 16 + lr;                                  \
            fah[i] = *(const bf16x8*)&lds[BUF][0][rm][swz(rm, lg) * 8];       \
            fal[i] = *(const bf16x8*)&lds[BUF][1][rm][swz(rm, lg) * 8];       \
            fbh[i] = *(const bf16x8*)&lds[BUF][2][rn][swz(rn, lg) * 8];       \
            fbl[i] = *(const bf16x8*)&lds[BUF][3][rn][swz(rn, lg) * 8];       \
        }                                                                     \
        _Pragma("unroll")                                                     \
        for (int i = 0; i < 4; ++i)                                           \
            _Pragma("unroll")                                                 \
            for (int j = 0; j < 4; ++j) {                                     \
                acc[i][j] = __builtin_amdgcn_mfma_f32_16x16x32_bf16(          \
                    fah[i], fbh[j], acc[i][j], 0, 0, 0);                      \
                acc[i][j] = __builtin_amdgcn_mfma_f32_16x16x32_bf16(          \
                    fah[i], fbl[j], acc[i][j], 0, 0, 0);                      \
                acc[i][j] = __builtin_amdgcn_mfma_f32_16x16x32_bf16(          \
                    fal[i], fbh[j], acc[i][j], 0, 0, 0);                      \
            }                                                                 \
    }

    // prologue: stage K-tile 0 into buffer 0
    G_LOAD(0);
    STAGE(0);

#pragma unroll 2
    for (int step = 0; step < 16; ++step) {
        const int cb = step & 1;
        __syncthreads();                 // staged writes of buf[cb] visible
        if (step < 15) G_LOAD((step + 1) * 32);  // prefetch overlaps MFMA
        COMPUTE(cb);
        if (step < 15) STAGE(cb ^ 1);
    }

#undef G_LOAD
#undef STAGE
#undef COMPUTE

    // epilogue: C/D frag mapping col = lane&15, row = (lane>>4)*4 + reg
#pragma unroll
    for (int i = 0; i < 4; ++i) {
#pragma unroll
        for (int r = 0; r < 4; ++r) {
            const int m = o0 + wm + i * 16 + lg * 4 + r;
            const float bias = bp[m];
            float* orow = out + ((size_t)b * 2 * CODE + CODE + m) * HW
                        + n0 + wn + lr;
#pragma unroll
            for (int j = 0; j < 4; ++j)
                orow[j * 16] = acc[i][j][r] + bias;
        }
    }
}

// ---------------------------------------------------------------------------
// Kernel 2: feat[b][c] = mean_n( x[b][c][n] * preds[b][n] )  -> fp32 ws
// grid (16 c-chunks, 32 b); preds staged in LDS once per block.
// ---------------------------------------------------------------------------
__global__ __launch_bounds__(256) void featmean_kernel(
    const float* __restrict__ preds,
    const float* __restrict__ out,
    float* __restrict__ featbuf)
{
    const int c0 = blockIdx.x * 16;
    const int b  = blockIdx.y;
    const int tid = threadIdx.x;
    const int w = tid >> 6, lane = tid & 63;

    __shared__ float sp[HW];
    const float* prow = preds + (size_t)b * HW;
#pragma unroll
    for (int j = 0; j < 4; ++j)
        *(floatx4*)&sp[tid * 4 + j * 1024] = *(const floatx4*)(prow + tid * 4 + j * 1024);
    __syncthreads();

    for (int cc = 0; cc < 4; ++cc) {
        const int c = c0 + w * 4 + cc;
        const float* xrow = out + ((size_t)b * 2 * CODE + CODE + c) * HW;
        float s = 0.f;
#pragma unroll 4
        for (int j = 0; j < 16; ++j) {
            floatx4 xv = *(const floatx4*)(xrow + lane * 4 + j * 256);
            floatx4 pv = *(const floatx4*)&sp[lane * 4 + j * 256];
            s += xv[0] * pv[0] + xv[1] * pv[1] + xv[2] * pv[2] + xv[3] * pv[3];
        }
        for (int off = 32; off > 0; off >>= 1) s += __shfl_down(s, off, 64);
        if (lane == 0) featbuf[b * CODE + c] = s * (1.f / HW);
    }
}

// ---------------------------------------------------------------------------
// Kernel 3: sequential EMA queue update (single block). qbuf = fp32 queue copy.
// upd[m][c] = logit[m]*f[c] / max(|logit[m]|*||f||, 1e-12); q[l]=0.9q[l]+0.1upd
// ---------------------------------------------------------------------------
__global__ __launch_bounds__(256) void scan_kernel(
    const float* __restrict__ queue_in,
    const float* __restrict__ featbuf,
    const int* __restrict__ labels,
    const int* __restrict__ flag,
    float* __restrict__ qbuf)
{
    const int tid = threadIdx.x;
    for (int i = tid; i < NCLS * MEM * CODE; i += 256)
        qbuf[i] = queue_in[i];
    __syncthreads();
    if (*flag != 1) return;

    __shared__ float sf[CODE];
    __shared__ float sred[256];
    __shared__ float slog[MEM];
    __shared__ float scoef[MEM];
    __shared__ float snorm;

    const int w = tid >> 6, lane = tid & 63;

    for (int b = 0; b < NB; ++b) {
        const int l = labels[b] & 3;           // labels are 0..3
        float f = featbuf[b * CODE + tid];
        sf[tid] = f;
        sred[tid] = f * f;
        __syncthreads();
        for (int st = 128; st > 0; st >>= 1) {
            if (tid < st) sred[tid] += sred[tid + st];
            __syncthreads();
        }
        if (tid == 0) snorm = sqrtf(sred[0]);
        __syncthreads();

        float* qrow = qbuf + (size_t)l * MEM * CODE;
        for (int mm = 0; mm < 5; ++mm) {
            int m = w * 5 + mm;
            float p = 0.f;
#pragma unroll
            for (int j = 0; j < 4; ++j) {
                int c = lane + 64 * j;
                p += qrow[m * CODE + c] * sf[c];
            }
            for (int off = 32; off > 0; off >>= 1) p += __shfl_down(p, off, 64);
            if (lane == 0) slog[m] = p;
        }
        __syncthreads();
        if (tid < MEM) {
            float lg = slog[tid];
            float denom = fmaxf(fabsf(lg) * snorm, 1e-12f);
            scoef[tid] = 0.1f * lg / denom;
        }
        __syncthreads();
        for (int m = 0; m < MEM; ++m) {
            int idx = m * CODE + tid;
            qrow[idx] = 0.9f * qrow[idx] + scoef[m] * sf[tid];
        }
        __syncthreads();
    }
}

// ---------------------------------------------------------------------------
// Kernel 4: attention. logit[m][n] = sum_c q[m][c] x[c][n]; softmax over m;
// new_feat[c][n] = sum_m q[m][c] attn[m][n] -> out[b][c][n] (first half)
// ---------------------------------------------------------------------------
__global__ __launch_bounds__(256) void attn_kernel(
    const float* __restrict__ qbuf,
    const int* __restrict__ labels,
    float* __restrict__ out)
{
    const int b = blockIdx.y;
    const int n = blockIdx.x * 256 + threadIdx.x;
    const int l = labels[b] & 3;

    __shared__ float sq[MEM * CODE];
    for (int i = threadIdx.x; i < MEM * CODE; i += 256)
        sq[i] = qbuf[(size_t)l * MEM * CODE + i];
    __syncthreads();

    const float* xb = out + ((size_t)b * 2 * CODE + CODE) * HW;

    float lg[MEM];
#pragma unroll
    for (int m = 0; m < MEM; ++m) lg[m] = 0.f;

    for (int c = 0; c < CODE; ++c) {
        float xv = xb[(size_t)c * HW + n];
#pragma unroll
        for (int m = 0; m < MEM; ++m) lg[m] += sq[m * CODE + c] * xv;
    }

    float mx = lg[0];
#pragma unroll
    for (int m = 1; m < MEM; ++m) mx = fmaxf(mx, lg[m]);
    float s = 0.f;
#pragma unroll
    for (int m = 0; m < MEM; ++m) { lg[m] = __expf(lg[m] - mx); s += lg[m]; }
    const float inv = 1.f / s;

    float* ob = out + (size_t)b * 2 * CODE * HW;
    for (int c = 0; c < CODE; ++c) {
        float acc = 0.f;
#pragma unroll
        for (int m = 0; m < MEM; ++m) acc += sq[m * CODE + c] * lg[m];
        ob[(size_t)c * HW + n] = acc * inv;
    }
}

// ---------------------------------------------------------------------------
extern "C" void kernel_launch(void* const* d_in, const int* in_sizes, int n_in,
                              void* d_out, int out_size, void* d_ws, size_t ws_size,
                              hipStream_t stream)
{
    const float* feats  = (const float*)d_in[0];
    const float* preds  = (const float*)d_in[1];
    const int*   labels = (const int*)d_in[2];
    const int*   flag   = (const int*)d_in[3];
    const float* queue  = (const float*)d_in[4];
    const float* Wp     = (const float*)d_in[5];
    const float* bp     = (const float*)d_in[6];
    float* out = (float*)d_out;

    float* featbuf = (float*)d_ws;                 // 32*256 fp32
    float* qbuf    = featbuf + NB * CODE;          // 4*20*256 fp32

    gemm_proj_bf16x3<<<dim3(HW / 128, CODE / 128, NB), 256, 0, stream>>>(feats, Wp, bp, out);
    featmean_kernel<<<dim3(16, NB), 256, 0, stream>>>(preds, out, featbuf);
    scan_kernel<<<1, 256, 0, stream>>>(queue, featbuf, labels, flag, qbuf);
    attn_kernel<<<dim3(HW / 256, NB), 256, 0, stream>>>(qbuf, labels, out);
}

// Round 2
// 597.653 us; speedup vs baseline: 1.5587x; 1.1140x over previous
//
#include <hip/hip_runtime.h>

typedef __attribute__((ext_vector_type(4))) float floatx4;
typedef __attribute__((ext_vector_type(8))) short bf16x8;
typedef __attribute__((ext_vector_type(2))) unsigned int uintx2;
typedef __attribute__((ext_vector_type(4))) unsigned int uintx4;

#define HW   4096
#define CIN  512
#define CODE 256
#define MEM  20
#define NCLS 4
#define NB   32

// ---------------------------------------------------------------------------
// fp32 -> bf16 round-to-nearest-even; returns rounded bits in HIGH 16 bits.
// ---------------------------------------------------------------------------
__device__ __forceinline__ unsigned bf16rn(float f) {
    unsigned u = __float_as_uint(f);
    return u + 0x7fffu + ((u >> 16) & 1u);
}

// LDS slot swizzle: 4 x 16B slots per 64B row, XOR by row bits 2..3
__device__ __forceinline__ int swz(int row, int slot) {
    return slot ^ ((row >> 2) & 3);
}

// ---------------------------------------------------------------------------
// Kernel 1: x = Wp @ feats + bp via bf16x3 split-precision MFMA. (unchanged)
// ---------------------------------------------------------------------------
__global__ __launch_bounds__(256, 2) void gemm_proj_bf16x3(
    const float* __restrict__ feats,
    const float* __restrict__ Wp,
    const float* __restrict__ bp,
    float* __restrict__ out)
{
    __shared__ unsigned short lds[2][4][128][32];

    const int b   = blockIdx.z;
    const int n0  = blockIdx.x * 128;
    const int o0  = blockIdx.y * 128;
    const int tid = threadIdx.x;
    const int lane = tid & 63;
    const int wid  = tid >> 6;
    const int wm = (wid >> 1) * 64;
    const int wn = (wid & 1) * 64;
    const int lr = lane & 15;
    const int lg = lane >> 4;

    const int ar = tid >> 3;
    const int ac = tid & 7;
    const int bn = tid & 127;
    const int bk = (tid >> 7) * 16;

    const float* fb = feats + (size_t)b * CIN * HW + n0 + bn;
    const float* wa = Wp + (size_t)(o0 + ar) * CIN + ac * 4;

    floatx4 acc[4][4];
#pragma unroll
    for (int i = 0; i < 4; ++i)
#pragma unroll
        for (int j = 0; j < 4; ++j)
#pragma unroll
            for (int r = 0; r < 4; ++r) acc[i][j][r] = 0.f;

    floatx4 av[4];
    float   bv[16];

#define G_LOAD(K0)                                                            \
    {                                                                         \
        _Pragma("unroll")                                                     \
        for (int i = 0; i < 4; ++i)                                           \
            av[i] = *(const floatx4*)(wa + (size_t)(32 * i) * CIN + (K0));    \
        _Pragma("unroll")                                                     \
        for (int j = 0; j < 16; ++j)                                          \
            bv[j] = fb[(size_t)((K0) + bk + j) * HW];                         \
    }

#define STAGE(BUF)                                                            \
    {                                                                         \
        _Pragma("unroll")                                                     \
        for (int i = 0; i < 4; ++i) {                                         \
            const int m = ar + 32 * i;                                        \
            unsigned h[4], l[4];                                              \
            _Pragma("unroll")                                                 \
            for (int e = 0; e < 4; ++e) {                                     \
                unsigned r = bf16rn(av[i][e]);                                \
                float hf = __uint_as_float(r & 0xffff0000u);                  \
                h[e] = r;                                                     \
                l[e] = bf16rn(av[i][e] - hf);                                 \
            }                                                                 \
            uintx2 tH, tL;                                                    \
            tH[0] = (h[0] >> 16) | (h[1] & 0xffff0000u);                      \
            tH[1] = (h[2] >> 16) | (h[3] & 0xffff0000u);                      \
            tL[0] = (l[0] >> 16) | (l[1] & 0xffff0000u);                      \
            tL[1] = (l[2] >> 16) | (l[3] & 0xffff0000u);                      \
            const int sA = swz(m, ac >> 1) * 8 + (ac & 1) * 4;                \
            *(uintx2*)&lds[BUF][0][m][sA] = tH;                               \
            *(uintx2*)&lds[BUF][1][m][sA] = tL;                               \
        }                                                                     \
        unsigned ph[8], pl[8];                                                \
        _Pragma("unroll")                                                     \
        for (int p = 0; p < 8; ++p) {                                         \
            unsigned r0 = bf16rn(bv[2 * p]), r1 = bf16rn(bv[2 * p + 1]);      \
            float h0 = __uint_as_float(r0 & 0xffff0000u);                     \
            float h1 = __uint_as_float(r1 & 0xffff0000u);                     \
            unsigned q0 = bf16rn(bv[2 * p] - h0);                             \
            unsigned q1 = bf16rn(bv[2 * p + 1] - h1);                         \
            ph[p] = (r0 >> 16) | (r1 & 0xffff0000u);                          \
            pl[p] = (q0 >> 16) | (q1 & 0xffff0000u);                          \
        }                                                                     \
        const int sb2 = (tid >> 7) * 2;                                       \
        _Pragma("unroll")                                                     \
        for (int u = 0; u < 2; ++u) {                                         \
            const int s = swz(bn, sb2 + u) * 8;                               \
            uintx4 tB, tC;                                                    \
            tB[0] = ph[4 * u];     tB[1] = ph[4 * u + 1];                     \
            tB[2] = ph[4 * u + 2]; tB[3] = ph[4 * u + 3];                     \
            tC[0] = pl[4 * u];     tC[1] = pl[4 * u + 1];                     \
            tC[2] = pl[4 * u + 2]; tC[3] = pl[4 * u + 3];                     \
            *(uintx4*)&lds[BUF][2][bn][s] = tB;                               \
            *(uintx4*)&lds[BUF][3][bn][s] = tC;                               \
        }                                                                     \
    }

#define COMPUTE(BUF)                                                          \
    {                                                                         \
        bf16x8 fah[4], fal[4], fbh[4], fbl[4];                                \
        _Pragma("unroll")                                                     \
        for (int i = 0; i < 4; ++i) {                                         \
            const int rm = wm + i * 16 + lr;                                  \
            const int rn = wn + i * 16 + lr;                                  \
            fah[i] = *(const bf16x8*)&lds[BUF][0][rm][swz(rm, lg) * 8];       \
            fal[i] = *(const bf16x8*)&lds[BUF][1][rm][swz(rm, lg) * 8];       \
            fbh[i] = *(const bf16x8*)&lds[BUF][2][rn][swz(rn, lg) * 8];       \
            fbl[i] = *(const bf16x8*)&lds[BUF][3][rn][swz(rn, lg) * 8];       \
        }                                                                     \
        _Pragma("unroll")                                                     \
        for (int i = 0; i < 4; ++i)                                           \
            _Pragma("unroll")                                                 \
            for (int j = 0; j < 4; ++j) {                                     \
                acc[i][j] = __builtin_amdgcn_mfma_f32_16x16x32_bf16(          \
                    fah[i], fbh[j], acc[i][j], 0, 0, 0);                      \
                acc[i][j] = __builtin_amdgcn_mfma_f32_16x16x32_bf16(          \
                    fah[i], fbl[j], acc[i][j], 0, 0, 0);                      \
                acc[i][j] = __builtin_amdgcn_mfma_f32_16x16x32_bf16(          \
                    fal[i], fbh[j], acc[i][j], 0, 0, 0);                      \
            }                                                                 \
    }

    G_LOAD(0);
    STAGE(0);

#pragma unroll 2
    for (int step = 0; step < 16; ++step) {
        const int cb = step & 1;
        __syncthreads();
        if (step < 15) G_LOAD((step + 1) * 32);
        COMPUTE(cb);
        if (step < 15) STAGE(cb ^ 1);
    }

#undef G_LOAD
#undef STAGE
#undef COMPUTE

#pragma unroll
    for (int i = 0; i < 4; ++i) {
#pragma unroll
        for (int r = 0; r < 4; ++r) {
            const int m = o0 + wm + i * 16 + lg * 4 + r;
            const float bias = bp[m];
            float* orow = out + ((size_t)b * 2 * CODE + CODE + m) * HW
                        + n0 + wn + lr;
#pragma unroll
            for (int j = 0; j < 4; ++j)
                orow[j * 16] = acc[i][j][r] + bias;
        }
    }
}

// ---------------------------------------------------------------------------
// Kernel 2: feat[b][c] = mean_n( x[b][c][n] * preds[b][n] )  (unchanged)
// ---------------------------------------------------------------------------
__global__ __launch_bounds__(256) void featmean_kernel(
    const float* __restrict__ preds,
    const float* __restrict__ out,
    float* __restrict__ featbuf)
{
    const int c0 = blockIdx.x * 16;
    const int b  = blockIdx.y;
    const int tid = threadIdx.x;
    const int w = tid >> 6, lane = tid & 63;

    __shared__ float sp[HW];
    const float* prow = preds + (size_t)b * HW;
#pragma unroll
    for (int j = 0; j < 4; ++j)
        *(floatx4*)&sp[tid * 4 + j * 1024] = *(const floatx4*)(prow + tid * 4 + j * 1024);
    __syncthreads();

    for (int cc = 0; cc < 4; ++cc) {
        const int c = c0 + w * 4 + cc;
        const float* xrow = out + ((size_t)b * 2 * CODE + CODE + c) * HW;
        float s = 0.f;
#pragma unroll 4
        for (int j = 0; j < 16; ++j) {
            floatx4 xv = *(const floatx4*)(xrow + lane * 4 + j * 256);
            floatx4 pv = *(const floatx4*)&sp[lane * 4 + j * 256];
            s += xv[0] * pv[0] + xv[1] * pv[1] + xv[2] * pv[2] + xv[3] * pv[3];
        }
        for (int off = 32; off > 0; off >>= 1) s += __shfl_down(s, off, 64);
        if (lane == 0) featbuf[b * CODE + c] = s * (1.f / HW);
    }
}

// ---------------------------------------------------------------------------
// Kernel 3: EMA queue update — one WAVE per class, zero barriers.
// Classes touch disjoint queue rows; sequence within a class preserved.
// Queue row (20x256 fp32) lives in 80 VGPRs/lane; reductions via shfl_xor.
// ---------------------------------------------------------------------------
__global__ __launch_bounds__(256) void scan_kernel(
    const float* __restrict__ queue_in,
    const float* __restrict__ featbuf,
    const int* __restrict__ labels,
    const int* __restrict__ flag,
    float* __restrict__ qbuf)
{
    const int tid  = threadIdx.x;
    const int w    = tid >> 6;      // class id (4 waves)
    const int lane = tid & 63;

    float qreg[MEM][4];
    const float* qr = queue_in + (size_t)w * MEM * CODE;
#pragma unroll
    for (int m = 0; m < MEM; ++m)
#pragma unroll
        for (int j = 0; j < 4; ++j)
            qreg[m][j] = qr[m * CODE + lane + 64 * j];

    if (*flag == 1) {
        for (int b = 0; b < NB; ++b) {
            const int l = labels[b] & 3;
            if (l != w) continue;
            float f[4];
#pragma unroll
            for (int j = 0; j < 4; ++j) f[j] = featbuf[b * CODE + lane + 64 * j];
            float n2 = f[0] * f[0] + f[1] * f[1] + f[2] * f[2] + f[3] * f[3];
#pragma unroll
            for (int off = 1; off < 64; off <<= 1) n2 += __shfl_xor(n2, off, 64);
            const float nrm = sqrtf(n2);
#pragma unroll
            for (int m = 0; m < MEM; ++m) {
                float p = qreg[m][0] * f[0] + qreg[m][1] * f[1]
                        + qreg[m][2] * f[2] + qreg[m][3] * f[3];
#pragma unroll
                for (int off = 1; off < 64; off <<= 1) p += __shfl_xor(p, off, 64);
                const float coef = 0.1f * p / fmaxf(fabsf(p) * nrm, 1e-12f);
#pragma unroll
                for (int j = 0; j < 4; ++j)
                    qreg[m][j] = 0.9f * qreg[m][j] + coef * f[j];
            }
        }
    }

    float* qo = qbuf + (size_t)w * MEM * CODE;
#pragma unroll
    for (int m = 0; m < MEM; ++m)
#pragma unroll
        for (int j = 0; j < 4; ++j)
            qo[m * CODE + lane + 64 * j] = qreg[m][j];
}

// ---------------------------------------------------------------------------
// Kernel 4: attention via MFMA.
//   logit = Q(20->32 pad) x X  : bf16x3 (qh*xh + qh*xl + ql*xh)
//   softmax over m in-register (D-layout: lane holds 8 of 32 m for one n;
//   2 shfl_xor finish the reduction); P -> bf16 via per-wave LDS bounce
//   PV: new_feat = Q^T x P      : bf16x2 (qTh*p + qTl*p)
// Block: one b, 256 n; 4 waves x 64 n; grid (16, 32).
// ---------------------------------------------------------------------------
__global__ __launch_bounds__(256, 2) void attn_mfma(
    const float* __restrict__ qbuf,
    const int* __restrict__ labels,
    float* __restrict__ out)
{
    __shared__ unsigned short sqh[32][256];   // q bf16 hi [m][c], slot-swizzled
    __shared__ unsigned short sql[32][256];   // q bf16 lo
    __shared__ unsigned short qth[256][40];   // qT bf16 hi [c][m], row=80B (16B-mult)
    __shared__ unsigned short qtl[256][40];   // qT bf16 lo
    __shared__ unsigned short pb[4][16][32];  // per-wave P bounce [n][m]

    const int b    = blockIdx.y;
    const int n0   = blockIdx.x * 256;
    const int tid  = threadIdx.x;
    const int lane = tid & 63;
    const int wid  = tid >> 6;
    const int lidx = lane & 15;
    const int g    = lane >> 4;
    const int l    = labels[b] & 3;

    // stage q (20x256, zero-pad to 32) as bf16 hi/lo, both layouts
    const float* qsrc = qbuf + (size_t)l * MEM * CODE;
    for (int idx = tid; idx < 32 * 256; idx += 256) {
        const int m = idx >> 8, c = idx & 255;
        const float v = (m < MEM) ? qsrc[m * CODE + c] : 0.f;
        const unsigned rh = bf16rn(v);
        const float hf = __uint_as_float(rh & 0xffff0000u);
        const unsigned rl = bf16rn(v - hf);
        const unsigned short h16 = (unsigned short)(rh >> 16);
        const unsigned short l16 = (unsigned short)(rl >> 16);
        const int cs = (((c >> 3) ^ (m & 7)) << 3) | (c & 7);
        sqh[m][cs] = h16;
        sql[m][cs] = l16;
        qth[c][m] = h16;
        qtl[c][m] = l16;
    }
    __syncthreads();

    const float* xb = out + ((size_t)b * 2 * CODE + CODE) * HW;
    float* ob = out + (size_t)b * 2 * CODE * HW;

    for (int ns = 0; ns < 4; ++ns) {
        const int nb = n0 + wid * 64 + ns * 16;
        const float* xcol = xb + nb + lidx;

        // ---- load this lane's x column slice: c = ks*32 + g*8 + j
        float xr[64];
#pragma unroll
        for (int ks = 0; ks < 8; ++ks)
#pragma unroll
            for (int j = 0; j < 8; ++j)
                xr[ks * 8 + j] = xcol[(size_t)(ks * 32 + g * 8 + j) * HW];

        floatx4 acc0 = {0.f, 0.f, 0.f, 0.f};
        floatx4 acc1 = {0.f, 0.f, 0.f, 0.f};

#pragma unroll
        for (int ks = 0; ks < 8; ++ks) {
            union { uintx4 u; bf16x8 v; } cvh, cvl;
#pragma unroll
            for (int p = 0; p < 4; ++p) {
                const float a0 = xr[ks * 8 + 2 * p];
                const float a1 = xr[ks * 8 + 2 * p + 1];
                const unsigned r0 = bf16rn(a0), r1 = bf16rn(a1);
                const float h0 = __uint_as_float(r0 & 0xffff0000u);
                const float h1 = __uint_as_float(r1 & 0xffff0000u);
                const unsigned q0 = bf16rn(a0 - h0), q1 = bf16rn(a1 - h1);
                cvh.u[p] = (r0 >> 16) | (r1 & 0xffff0000u);
                cvl.u[p] = (q0 >> 16) | (q1 & 0xffff0000u);
            }
            const int s2 = ((ks * 4 + g) ^ (lidx & 7)) * 8;
            const bf16x8 a0h = *(const bf16x8*)&sqh[lidx][s2];
            const bf16x8 a0l = *(const bf16x8*)&sql[lidx][s2];
            const bf16x8 a1h = *(const bf16x8*)&sqh[16 + lidx][s2];
            const bf16x8 a1l = *(const bf16x8*)&sql[16 + lidx][s2];
            acc0 = __builtin_amdgcn_mfma_f32_16x16x32_bf16(a0h, cvh.v, acc0, 0, 0, 0);
            acc0 = __builtin_amdgcn_mfma_f32_16x16x32_bf16(a0h, cvl.v, acc0, 0, 0, 0);
            acc0 = __builtin_amdgcn_mfma_f32_16x16x32_bf16(a0l, cvh.v, acc0, 0, 0, 0);
            acc1 = __builtin_amdgcn_mfma_f32_16x16x32_bf16(a1h, cvh.v, acc1, 0, 0, 0);
            acc1 = __builtin_amdgcn_mfma_f32_16x16x32_bf16(a1h, cvl.v, acc1, 0, 0, 0);
            acc1 = __builtin_amdgcn_mfma_f32_16x16x32_bf16(a1l, cvh.v, acc1, 0, 0, 0);
        }

        // ---- softmax over m (valid m: tile0 all 16; tile1 only g==0 -> m 16..19)
        float mx = fmaxf(fmaxf(acc0[0], acc0[1]), fmaxf(acc0[2], acc0[3]));
        if (g == 0)
            mx = fmaxf(mx, fmaxf(fmaxf(acc1[0], acc1[1]), fmaxf(acc1[2], acc1[3])));
        mx = fmaxf(mx, __shfl_xor(mx, 16, 64));
        mx = fmaxf(mx, __shfl_xor(mx, 32, 64));

        float e0[4], e1[4], s = 0.f;
#pragma unroll
        for (int r = 0; r < 4; ++r) { e0[r] = __expf(acc0[r] - mx); s += e0[r]; }
#pragma unroll
        for (int r = 0; r < 4; ++r) {
            e1[r] = (g == 0) ? __expf(acc1[r] - mx) : 0.f;
            s += e1[r];
        }
        s += __shfl_xor(s, 16, 64);
        s += __shfl_xor(s, 32, 64);
        const float inv = 1.f / s;

        // ---- P -> bf16, bounce through per-wave LDS tile [n][m]
        const unsigned pw0 = (bf16rn(e0[0] * inv) >> 16) | (bf16rn(e0[1] * inv) & 0xffff0000u);
        const unsigned pw1 = (bf16rn(e0[2] * inv) >> 16) | (bf16rn(e0[3] * inv) & 0xffff0000u);
        const unsigned pw2 = (bf16rn(e1[0] * inv) >> 16) | (bf16rn(e1[1] * inv) & 0xffff0000u);
        const unsigned pw3 = (bf16rn(e1[2] * inv) >> 16) | (bf16rn(e1[3] * inv) & 0xffff0000u);
        *(unsigned*)&pb[wid][lidx][g * 4]          = pw0;
        *(unsigned*)&pb[wid][lidx][g * 4 + 2]      = pw1;
        *(unsigned*)&pb[wid][lidx][16 + g * 4]     = pw2;
        *(unsigned*)&pb[wid][lidx][16 + g * 4 + 2] = pw3;
        // same-wave producer/consumer: no barrier needed, compiler orders via lgkmcnt

        const bf16x8 pfrag = *(const bf16x8*)&pb[wid][lidx][g * 8];

        // ---- PV: new_feat[c][n] = sum_m qT[c][m] * P[m][n]
#pragma unroll
        for (int ct = 0; ct < 16; ++ct) {
            const bf16x8 ath = *(const bf16x8*)&qth[ct * 16 + lidx][g * 8];
            const bf16x8 atl = *(const bf16x8*)&qtl[ct * 16 + lidx][g * 8];
            floatx4 f4 = {0.f, 0.f, 0.f, 0.f};
            f4 = __builtin_amdgcn_mfma_f32_16x16x32_bf16(ath, pfrag, f4, 0, 0, 0);
            f4 = __builtin_amdgcn_mfma_f32_16x16x32_bf16(atl, pfrag, f4, 0, 0, 0);
            float* orow = ob + (size_t)(ct * 16 + g * 4) * HW + nb + lidx;
#pragma unroll
            for (int r = 0; r < 4; ++r) orow[(size_t)r * HW] = f4[r];
        }
    }
}

// ---------------------------------------------------------------------------
extern "C" void kernel_launch(void* const* d_in, const int* in_sizes, int n_in,
                              void* d_out, int out_size, void* d_ws, size_t ws_size,
                              hipStream_t stream)
{
    const float* feats  = (const float*)d_in[0];
    const float* preds  = (const float*)d_in[1];
    const int*   labels = (const int*)d_in[2];
    const int*   flag   = (const int*)d_in[3];
    const float* queue  = (const float*)d_in[4];
    const float* Wp     = (const float*)d_in[5];
    const float* bp     = (const float*)d_in[6];
    float* out = (float*)d_out;

    float* featbuf = (float*)d_ws;                 // 32*256 fp32
    float* qbuf    = featbuf + NB * CODE;          // 4*20*256 fp32

    gemm_proj_bf16x3<<<dim3(HW / 128, CODE / 128, NB), 256, 0, stream>>>(feats, Wp, bp, out);
    featmean_kernel<<<dim3(16, NB), 256, 0, stream>>>(preds, out, featbuf);
    scan_kernel<<<1, 256, 0, stream>>>(queue, featbuf, labels, flag, qbuf);
    attn_mfma<<<dim3(HW / 256, NB), 256, 0, stream>>>(qbuf, labels, out);
}

// Round 4
// 595.219 us; speedup vs baseline: 1.5651x; 1.0041x over previous
//
#include <hip/hip_runtime.h>

typedef __attribute__((ext_vector_type(4))) float floatx4;
typedef __attribute__((ext_vector_type(8))) short bf16x8;
typedef __attribute__((ext_vector_type(2))) unsigned int uintx2;
typedef __attribute__((ext_vector_type(4))) unsigned int uintx4;

#define HW   4096
#define CIN  512
#define CODE 256
#define MEM  20
#define NCLS 4
#define NB   32

// ---------------------------------------------------------------------------
// fp32 -> bf16 helpers.
// bf16rn: manual RNE, bits in HIGH 16 (used only in cold staging paths).
// cvt_pk_bf16: HW packed convert, low16 = bf16(a), high16 = bf16(b).
// split2: hi/lo split of a pair -> {packed hi word, packed lo word} by value.
//   (bf16x3 is self-correcting: lo captures whatever rounding hi used.)
// ---------------------------------------------------------------------------
__device__ __forceinline__ unsigned bf16rn(float f) {
    unsigned u = __float_as_uint(f);
    return u + 0x7fffu + ((u >> 16) & 1u);
}

__device__ __forceinline__ unsigned cvt_pk_bf16(float a, float b) {
    unsigned r;
    asm("v_cvt_pk_bf16_f32 %0, %1, %2" : "=v"(r) : "v"(a), "v"(b));
    return r;
}

struct hl2 { unsigned h, l; };

__device__ __forceinline__ hl2 split2(float a, float b) {
    hl2 r;
    r.h = cvt_pk_bf16(a, b);
    const float ha = __uint_as_float(r.h << 16);
    const float hb = __uint_as_float(r.h & 0xffff0000u);
    r.l = cvt_pk_bf16(a - ha, b - hb);
    return r;
}

// LDS slot swizzle: 4 x 16B slots per 64B row, XOR by row bits 2..3
__device__ __forceinline__ int swz(int row, int slot) {
    return slot ^ ((row >> 2) & 3);
}

// ---------------------------------------------------------------------------
// Kernel 0: zero featbuf (32*256 fp32) for the fused-featmean atomics.
// ---------------------------------------------------------------------------
__global__ __launch_bounds__(256) void zero_featbuf(float* __restrict__ featbuf)
{
    featbuf[blockIdx.x * 256 + threadIdx.x] = 0.f;
}

// ---------------------------------------------------------------------------
// Kernel 1: x = Wp @ feats + bp via bf16x3 split-precision MFMA,
// with featmean fused into the epilogue:
//   featbuf[b][m] += sum_n x[m][n]*preds[n] / HW   (device-scope atomics)
// Tile 128(o) x 128(n), BK=32, 4 waves, double-buffered LDS (64 KiB).
// ---------------------------------------------------------------------------
__global__ __launch_bounds__(256, 2) void gemm_proj_bf16x3(
    const float* __restrict__ feats,
    const float* __restrict__ Wp,
    const float* __restrict__ bp,
    const float* __restrict__ preds,
    float* __restrict__ featbuf,
    float* __restrict__ out)
{
    __shared__ unsigned short lds[2][4][128][32];

    const int b   = blockIdx.z;
    const int n0  = blockIdx.x * 128;
    const int o0  = blockIdx.y * 128;
    const int tid = threadIdx.x;
    const int lane = tid & 63;
    const int wid  = tid >> 6;
    const int wm = (wid >> 1) * 64;
    const int wn = (wid & 1) * 64;
    const int lr = lane & 15;
    const int lg = lane >> 4;

    const int ar = tid >> 3;
    const int ac = tid & 7;
    const int bn = tid & 127;
    const int bk = (tid >> 7) * 16;

    const float* fb = feats + (size_t)b * CIN * HW + n0 + bn;
    const float* wa = Wp + (size_t)(o0 + ar) * CIN + ac * 4;

    floatx4 acc[4][4];
#pragma unroll
    for (int i = 0; i < 4; ++i)
#pragma unroll
        for (int j = 0; j < 4; ++j)
#pragma unroll
            for (int r = 0; r < 4; ++r) acc[i][j][r] = 0.f;

    floatx4 av[4];
    float   bv[16];

#define G_LOAD(K0)                                                            \
    {                                                                         \
        _Pragma("unroll")                                                     \
        for (int i = 0; i < 4; ++i)                                           \
            av[i] = *(const floatx4*)(wa + (size_t)(32 * i) * CIN + (K0));    \
        _Pragma("unroll")                                                     \
        for (int j = 0; j < 16; ++j)                                          \
            bv[j] = fb[(size_t)((K0) + bk + j) * HW];                         \
    }

#define STAGE(BUF)                                                            \
    {                                                                         \
        _Pragma("unroll")                                                     \
        for (int i = 0; i < 4; ++i) {                                         \
            const int m = ar + 32 * i;                                        \
            const hl2 s01 = split2(av[i][0], av[i][1]);                       \
            const hl2 s23 = split2(av[i][2], av[i][3]);                       \
            uintx2 tH, tL;                                                    \
            tH[0] = s01.h; tH[1] = s23.h;                                     \
            tL[0] = s01.l; tL[1] = s23.l;                                     \
            const int sA = swz(m, ac >> 1) * 8 + (ac & 1) * 4;                \
            *(uintx2*)&lds[BUF][0][m][sA] = tH;                               \
            *(uintx2*)&lds[BUF][1][m][sA] = tL;                               \
        }                                                                     \
        unsigned ph[8], pl[8];                                                \
        _Pragma("unroll")                                                     \
        for (int p = 0; p < 8; ++p) {                                         \
            const hl2 sp = split2(bv[2 * p], bv[2 * p + 1]);                  \
            ph[p] = sp.h; pl[p] = sp.l;                                       \
        }                                                                     \
        const int sb2 = (tid >> 7) * 2;                                       \
        _Pragma("unroll")                                                     \
        for (int u = 0; u < 2; ++u) {                                         \
            const int s = swz(bn, sb2 + u) * 8;                               \
            uintx4 tB, tC;                                                    \
            tB[0] = ph[4 * u];     tB[1] = ph[4 * u + 1];                     \
            tB[2] = ph[4 * u + 2]; tB[3] = ph[4 * u + 3];                     \
            tC[0] = pl[4 * u];     tC[1] = pl[4 * u + 1];                     \
            tC[2] = pl[4 * u + 2]; tC[3] = pl[4 * u + 3];                     \
            *(uintx4*)&lds[BUF][2][bn][s] = tB;                               \
            *(uintx4*)&lds[BUF][3][bn][s] = tC;                               \
        }                                                                     \
    }

#define COMPUTE(BUF)                                                          \
    {                                                                         \
        bf16x8 fah[4], fal[4], fbh[4], fbl[4];                                \
        _Pragma("unroll")                                                     \
        for (int i = 0; i < 4; ++i) {                                         \
            const int rm = wm + i * 16 + lr;                                  \
            const int rn = wn + i * 16 + lr;                                  \
            fah[i] = *(const bf16x8*)&lds[BUF][0][rm][swz(rm, lg) * 8];       \
            fal[i] = *(const bf16x8*)&lds[BUF][1][rm][swz(rm, lg) * 8];       \
            fbh[i] = *(const bf16x8*)&lds[BUF][2][rn][swz(rn, lg) * 8];       \
            fbl[i] = *(const bf16x8*)&lds[BUF][3][rn][swz(rn, lg) * 8];       \
        }                                                                     \
        _Pragma("unroll")                                                     \
        for (int i = 0; i < 4; ++i)                                           \
            _Pragma("unroll")                                                 \
            for (int j = 0; j < 4; ++j) {                                     \
                acc[i][j] = __builtin_amdgcn_mfma_f32_16x16x32_bf16(          \
                    fah[i], fbh[j], acc[i][j], 0, 0, 0);                      \
                acc[i][j] = __builtin_amdgcn_mfma_f32_16x16x32_bf16(          \
                    fah[i], fbl[j], acc[i][j], 0, 0, 0);                      \
                acc[i][j] = __builtin_amdgcn_mfma_f32_16x16x32_bf16(          \
                    fal[i], fbh[j], acc[i][j], 0, 0, 0);                      \
            }                                                                 \
    }

    G_LOAD(0);
    STAGE(0);

#pragma unroll 2
    for (int step = 0; step < 16; ++step) {
        const int cb = step & 1;
        __syncthreads();
        if (step < 15) G_LOAD((step + 1) * 32);
        COMPUTE(cb);
        if (step < 15) STAGE(cb ^ 1);
    }

#undef G_LOAD
#undef STAGE
#undef COMPUTE

    // epilogue: C-write + fused featmean partial.
    // D frag: m = wm+i*16+lg*4+r, n = wn+j*16+lr.
    float pv[4];
#pragma unroll
    for (int j = 0; j < 4; ++j)
        pv[j] = preds[(size_t)b * HW + n0 + wn + j * 16 + lr];

#pragma unroll
    for (int i = 0; i < 4; ++i) {
#pragma unroll
        for (int r = 0; r < 4; ++r) {
            const int m = o0 + wm + i * 16 + lg * 4 + r;
            const float bias = bp[m];
            float* orow = out + ((size_t)b * 2 * CODE + CODE + m) * HW
                        + n0 + wn + lr;
            float part = 0.f;
#pragma unroll
            for (int j = 0; j < 4; ++j) {
                const float xv = acc[i][j][r] + bias;
                orow[j * 16] = xv;
                part += xv * pv[j];
            }
            // reduce over the 16-lane group (lanes span n for fixed m)
            part += __shfl_xor(part, 1, 64);
            part += __shfl_xor(part, 2, 64);
            part += __shfl_xor(part, 4, 64);
            part += __shfl_xor(part, 8, 64);
            if (lr == 0)
                atomicAdd(&featbuf[b * CODE + m], part * (1.f / HW));
        }
    }
}

// ---------------------------------------------------------------------------
// Kernel 3: EMA queue update — one WAVE per class, zero barriers.
// ---------------------------------------------------------------------------
__global__ __launch_bounds__(256) void scan_kernel(
    const float* __restrict__ queue_in,
    const float* __restrict__ featbuf,
    const int* __restrict__ labels,
    const int* __restrict__ flag,
    float* __restrict__ qbuf)
{
    const int tid  = threadIdx.x;
    const int w    = tid >> 6;      // class id (4 waves)
    const int lane = tid & 63;

    float qreg[MEM][4];
    const float* qr = queue_in + (size_t)w * MEM * CODE;
#pragma unroll
    for (int m = 0; m < MEM; ++m)
#pragma unroll
        for (int j = 0; j < 4; ++j)
            qreg[m][j] = qr[m * CODE + lane + 64 * j];

    if (*flag == 1) {
        for (int b = 0; b < NB; ++b) {
            const int l = labels[b] & 3;
            if (l != w) continue;
            float f[4];
#pragma unroll
            for (int j = 0; j < 4; ++j) f[j] = featbuf[b * CODE + lane + 64 * j];
            float n2 = f[0] * f[0] + f[1] * f[1] + f[2] * f[2] + f[3] * f[3];
#pragma unroll
            for (int off = 1; off < 64; off <<= 1) n2 += __shfl_xor(n2, off, 64);
            const float nrm = sqrtf(n2);
#pragma unroll
            for (int m = 0; m < MEM; ++m) {
                float p = qreg[m][0] * f[0] + qreg[m][1] * f[1]
                        + qreg[m][2] * f[2] + qreg[m][3] * f[3];
#pragma unroll
                for (int off = 1; off < 64; off <<= 1) p += __shfl_xor(p, off, 64);
                const float coef = 0.1f * p / fmaxf(fabsf(p) * nrm, 1e-12f);
#pragma unroll
                for (int j = 0; j < 4; ++j)
                    qreg[m][j] = 0.9f * qreg[m][j] + coef * f[j];
            }
        }
    }

    float* qo = qbuf + (size_t)w * MEM * CODE;
#pragma unroll
    for (int m = 0; m < MEM; ++m)
#pragma unroll
        for (int j = 0; j < 4; ++j)
            qo[m * CODE + lane + 64 * j] = qreg[m][j];
}

// ---------------------------------------------------------------------------
// Kernel 4: attention via MFMA (cvt_pk conversions).
// ---------------------------------------------------------------------------
__global__ __launch_bounds__(256, 2) void attn_mfma(
    const float* __restrict__ qbuf,
    const int* __restrict__ labels,
    float* __restrict__ out)
{
    __shared__ unsigned short sqh[32][256];   // q bf16 hi [m][c], slot-swizzled
    __shared__ unsigned short sql[32][256];   // q bf16 lo
    __shared__ unsigned short qth[256][40];   // qT bf16 hi [c][m]
    __shared__ unsigned short qtl[256][40];   // qT bf16 lo
    __shared__ unsigned short pb[4][16][32];  // per-wave P bounce [n][m]

    const int b    = blockIdx.y;
    const int n0   = blockIdx.x * 256;
    const int tid  = threadIdx.x;
    const int lane = tid & 63;
    const int wid  = tid >> 6;
    const int lidx = lane & 15;
    const int g    = lane >> 4;
    const int l    = labels[b] & 3;

    const float* qsrc = qbuf + (size_t)l * MEM * CODE;
    for (int idx = tid; idx < 32 * 256; idx += 256) {
        const int m = idx >> 8, c = idx & 255;
        const float v = (m < MEM) ? qsrc[m * CODE + c] : 0.f;
        const unsigned rh = bf16rn(v);
        const float hf = __uint_as_float(rh & 0xffff0000u);
        const unsigned rl = bf16rn(v - hf);
        const unsigned short h16 = (unsigned short)(rh >> 16);
        const unsigned short l16 = (unsigned short)(rl >> 16);
        const int cs = (((c >> 3) ^ (m & 7)) << 3) | (c & 7);
        sqh[m][cs] = h16;
        sql[m][cs] = l16;
        qth[c][m] = h16;
        qtl[c][m] = l16;
    }
    __syncthreads();

    const float* xb = out + ((size_t)b * 2 * CODE + CODE) * HW;
    float* ob = out + (size_t)b * 2 * CODE * HW;

    for (int ns = 0; ns < 4; ++ns) {
        const int nb = n0 + wid * 64 + ns * 16;
        const float* xcol = xb + nb + lidx;

        float xr[64];
#pragma unroll
        for (int ks = 0; ks < 8; ++ks)
#pragma unroll
            for (int j = 0; j < 8; ++j)
                xr[ks * 8 + j] = xcol[(size_t)(ks * 32 + g * 8 + j) * HW];

        floatx4 acc0 = {0.f, 0.f, 0.f, 0.f};
        floatx4 acc1 = {0.f, 0.f, 0.f, 0.f};

#pragma unroll
        for (int ks = 0; ks < 8; ++ks) {
            union { uintx4 u; bf16x8 v; } cvh, cvl;
#pragma unroll
            for (int p = 0; p < 4; ++p) {
                const hl2 sp = split2(xr[ks * 8 + 2 * p], xr[ks * 8 + 2 * p + 1]);
                cvh.u[p] = sp.h;
                cvl.u[p] = sp.l;
            }
            const int s2 = ((ks * 4 + g) ^ (lidx & 7)) * 8;
            const bf16x8 a0h = *(const bf16x8*)&sqh[lidx][s2];
            const bf16x8 a0l = *(const bf16x8*)&sql[lidx][s2];
            const bf16x8 a1h = *(const bf16x8*)&sqh[16 + lidx][s2];
            const bf16x8 a1l = *(const bf16x8*)&sql[16 + lidx][s2];
            acc0 = __builtin_amdgcn_mfma_f32_16x16x32_bf16(a0h, cvh.v, acc0, 0, 0, 0);
            acc0 = __builtin_amdgcn_mfma_f32_16x16x32_bf16(a0h, cvl.v, acc0, 0, 0, 0);
            acc0 = __builtin_amdgcn_mfma_f32_16x16x32_bf16(a0l, cvh.v, acc0, 0, 0, 0);
            acc1 = __builtin_amdgcn_mfma_f32_16x16x32_bf16(a1h, cvh.v, acc1, 0, 0, 0);
            acc1 = __builtin_amdgcn_mfma_f32_16x16x32_bf16(a1h, cvl.v, acc1, 0, 0, 0);
            acc1 = __builtin_amdgcn_mfma_f32_16x16x32_bf16(a1l, cvh.v, acc1, 0, 0, 0);
        }

        float mx = fmaxf(fmaxf(acc0[0], acc0[1]), fmaxf(acc0[2], acc0[3]));
        if (g == 0)
            mx = fmaxf(mx, fmaxf(fmaxf(acc1[0], acc1[1]), fmaxf(acc1[2], acc1[3])));
        mx = fmaxf(mx, __shfl_xor(mx, 16, 64));
        mx = fmaxf(mx, __shfl_xor(mx, 32, 64));

        float e0[4], e1[4], s = 0.f;
#pragma unroll
        for (int r = 0; r < 4; ++r) { e0[r] = __expf(acc0[r] - mx); s += e0[r]; }
#pragma unroll
        for (int r = 0; r < 4; ++r) {
            e1[r] = (g == 0) ? __expf(acc1[r] - mx) : 0.f;
            s += e1[r];
        }
        s += __shfl_xor(s, 16, 64);
        s += __shfl_xor(s, 32, 64);
        const float inv = 1.f / s;

        const unsigned pw0 = cvt_pk_bf16(e0[0] * inv, e0[1] * inv);
        const unsigned pw1 = cvt_pk_bf16(e0[2] * inv, e0[3] * inv);
        const unsigned pw2 = cvt_pk_bf16(e1[0] * inv, e1[1] * inv);
        const unsigned pw3 = cvt_pk_bf16(e1[2] * inv, e1[3] * inv);
        *(unsigned*)&pb[wid][lidx][g * 4]          = pw0;
        *(unsigned*)&pb[wid][lidx][g * 4 + 2]      = pw1;
        *(unsigned*)&pb[wid][lidx][16 + g * 4]     = pw2;
        *(unsigned*)&pb[wid][lidx][16 + g * 4 + 2] = pw3;
        // same-wave producer/consumer: compiler orders via lgkmcnt

        const bf16x8 pfrag = *(const bf16x8*)&pb[wid][lidx][g * 8];

#pragma unroll
        for (int ct = 0; ct < 16; ++ct) {
            const bf16x8 ath = *(const bf16x8*)&qth[ct * 16 + lidx][g * 8];
            const bf16x8 atl = *(const bf16x8*)&qtl[ct * 16 + lidx][g * 8];
            floatx4 f4 = {0.f, 0.f, 0.f, 0.f};
            f4 = __builtin_amdgcn_mfma_f32_16x16x32_bf16(ath, pfrag, f4, 0, 0, 0);
            f4 = __builtin_amdgcn_mfma_f32_16x16x32_bf16(atl, pfrag, f4, 0, 0, 0);
            float* orow = ob + (size_t)(ct * 16 + g * 4) * HW + nb + lidx;
#pragma unroll
            for (int r = 0; r < 4; ++r) orow[(size_t)r * HW] = f4[r];
        }
    }
}

// ---------------------------------------------------------------------------
extern "C" void kernel_launch(void* const* d_in, const int* in_sizes, int n_in,
                              void* d_out, int out_size, void* d_ws, size_t ws_size,
                              hipStream_t stream)
{
    const float* feats  = (const float*)d_in[0];
    const float* preds  = (const float*)d_in[1];
    const int*   labels = (const int*)d_in[2];
    const int*   flag   = (const int*)d_in[3];
    const float* queue  = (const float*)d_in[4];
    const float* Wp     = (const float*)d_in[5];
    const float* bp     = (const float*)d_in[6];
    float* out = (float*)d_out;

    float* featbuf = (float*)d_ws;                 // 32*256 fp32
    float* qbuf    = featbuf + NB * CODE;          // 4*20*256 fp32

    zero_featbuf<<<dim3(NB), 256, 0, stream>>>(featbuf);
    gemm_proj_bf16x3<<<dim3(HW / 128, CODE / 128, NB), 256, 0, stream>>>(
        feats, Wp, bp, preds, featbuf, out);
    scan_kernel<<<1, 256, 0, stream>>>(queue, featbuf, labels, flag, qbuf);
    attn_mfma<<<dim3(HW / 256, NB), 256, 0, stream>>>(qbuf, labels, out);
}